// Round 4
// baseline (56.165 us; speedup 1.0000x reference)
//
#include <hip/hip_runtime.h>

#define F_IN  128
#define HID   16
#define CF_IN 64
#define TILE  64          // nodes per node-block
#define NTHR  256

// ---- shared-memory float offsets (node path) ----
#define XS    0           // x tile [64][132], pad->16B-aligned rows
#define XPAD  132
#define W1S   8448        // [128][16]
#define B1S   10496       // [16]
#define W2S   10512       // [16][16]
#define B2S   10768       // [16]
#define WNS   10784       // [16]
#define H1S   10800       // [64][20]
#define H1P   20
#define BNS   12080       // [1]
#define PSS   12084       // [4 waves][B<=8]
#define SMEM_FLOATS 12120
// ---- col path reuses the same buffer ----
#define CW1   0           // [64][16]
#define CB1   1024
#define CW2   1040
#define CB2   1056
#define CPS   1060        // [4][B<=8]

// GCN aggregation is exactly the identity here (row==col after the reference's
// broadcast+reshape), so each conv is x@W + b. edge_index is never read.
// All weights live in LDS and are read with uniform-address (broadcast)
// ds_read_b128 -> cheap regardless of whether the compiler scalarizes.

__global__ __launch_bounds__(NTHR) void fused_kernel(
    const float* __restrict__ x, const float* __restrict__ xc,
    const float* __restrict__ W1, const float* __restrict__ b1,
    const float* __restrict__ W2, const float* __restrict__ b2,
    const float* __restrict__ Wn, const float* __restrict__ bn,
    const float* __restrict__ Wc1, const float* __restrict__ bc1,
    const float* __restrict__ Wc2, const float* __restrict__ bc2,
    float* __restrict__ pN, float* __restrict__ pC,
    int totalN, int N, int B, int C, int nodeBlocks, int colBlocks)
{
    __shared__ __align__(16) float sm[SMEM_FLOATS];
    float4* sm4 = (float4*)sm;
    const int t = threadIdx.x;
    const int bx = blockIdx.x;
    const int wave = t >> 6;

    if (bx < nodeBlocks) {
        // ---- issue x tile loads first (flat contiguous, fill-like) ----
        const long tileF4 = (long)bx * (TILE * F_IN / 4);
        const long maxF4  = (long)totalN * (F_IN / 4) - 1;
        const float4* __restrict__ gx = (const float4*)x;
        float4 v[8];
#pragma unroll
        for (int g = 0; g < 8; ++g) {
            long f4 = tileF4 + g * NTHR + t;
            if (f4 > maxF4) f4 = maxF4;           // tail clamp (masked later)
            v[g] = gx[f4];
        }

        // ---- stage weights while x loads are in flight ----
        const float4* __restrict__ gW1 = (const float4*)W1;
#pragma unroll
        for (int i = 0; i < 2; ++i)               // 512 float4
            sm4[W1S / 4 + i * NTHR + t] = gW1[i * NTHR + t];
        if (t < HID * HID / 4) sm4[W2S / 4 + t] = ((const float4*)W2)[t];
        if (t < HID) { sm[B1S + t] = b1[t]; sm[B2S + t] = b2[t]; sm[WNS + t] = Wn[t]; }
        if (t == 0)  sm[BNS] = bn[0];

        // ---- x -> LDS row-major [n][132] (b128 writes, zero wasted bank cycles)
#pragma unroll
        for (int g = 0; g < 8; ++g) {
            const int f = g * NTHR + t;
            const int n = f >> 5, k4 = f & 31;
            *(float4*)&sm[XS + n * XPAD + 4 * k4] = v[g];
        }
        __syncthreads();

        // ---- layer 1: thread = (node n, j-quad jg) ----
        const int n = t >> 2, jg = t & 3;
        float4 acc = *(const float4*)&sm[B1S + 4 * jg];
        const float* __restrict__ xrow = &sm[XS + n * XPAD];
        const float* __restrict__ w1b  = &sm[W1S + 4 * jg];
#pragma unroll
        for (int k4 = 0; k4 < 32; ++k4) {
            const float4 xv = *(const float4*)&xrow[4 * k4];
#pragma unroll
            for (int r = 0; r < 4; ++r) {
                const float4 w = *(const float4*)&w1b[(4 * k4 + r) * HID];
                const float xs = (r == 0) ? xv.x : (r == 1) ? xv.y
                               : (r == 2) ? xv.z : xv.w;
                acc.x = fmaf(xs, w.x, acc.x);
                acc.y = fmaf(xs, w.y, acc.y);
                acc.z = fmaf(xs, w.z, acc.z);
                acc.w = fmaf(xs, w.w, acc.w);
            }
        }
        float4 h1v;
        h1v.x = fmaxf(acc.x, 0.f); h1v.y = fmaxf(acc.y, 0.f);
        h1v.z = fmaxf(acc.z, 0.f); h1v.w = fmaxf(acc.w, 0.f);
        *(float4*)&sm[H1S + n * H1P + 4 * jg] = h1v;
        __syncthreads();

        // ---- layer 2 (16x16) ----
        float4 a2 = *(const float4*)&sm[B2S + 4 * jg];
#pragma unroll
        for (int k = 0; k < HID; ++k) {
            const float hk = sm[H1S + n * H1P + k];
            const float4 w = *(const float4*)&sm[W2S + k * HID + 4 * jg];
            a2.x = fmaf(hk, w.x, a2.x);
            a2.y = fmaf(hk, w.y, a2.y);
            a2.z = fmaf(hk, w.z, a2.z);
            a2.w = fmaf(hk, w.w, a2.w);
        }
        // ---- layer 3 partial + jg reduce ----
        const float4 wn = *(const float4*)&sm[WNS + 4 * jg];
        float o = fmaxf(a2.x, 0.f) * wn.x + fmaxf(a2.y, 0.f) * wn.y
                + fmaxf(a2.z, 0.f) * wn.z + fmaxf(a2.w, 0.f) * wn.w;
        o += __shfl_xor(o, 1, 64);
        o += __shfl_xor(o, 2, 64);      // all 4 jg lanes now hold full o(n)

        const int node = bx * TILE + n;
        const int myb  = node / N;
        const float contrib = (jg == 0 && node < totalN) ? (o + sm[BNS]) : 0.f;
        for (int b = 0; b < B; ++b) {
            float s = (myb == b) ? contrib : 0.f;
#pragma unroll
            for (int off = 32; off; off >>= 1) s += __shfl_down(s, off, 64);
            if ((t & 63) == 0) sm[PSS + wave * B + b] = s;
        }
        __syncthreads();
        if (t == 0) {
            for (int b = 0; b < B; ++b)
                pN[(long)b * nodeBlocks + bx] =
                    (sm[PSS + 0 * B + b] + sm[PSS + 1 * B + b]) +
                    (sm[PSS + 2 * B + b] + sm[PSS + 3 * B + b]);
        }
    } else {
        // ---------------- col path ----------------
        const int cb = bx - nodeBlocks;
        const float4* __restrict__ gWc1 = (const float4*)Wc1;
        if (t < CF_IN * HID / 4) sm4[CW1 / 4 + t] = gWc1[t];   // 256 float4
        if (t < HID) { sm[CB1 + t] = bc1[t]; sm[CW2 + t] = Wc2[t]; }
        if (t == 0)  sm[CB2] = bc2[0];
        __syncthreads();

        const int totC = B * C;
        const int c  = cb * NTHR + t;
        const int cc = (c < totC) ? c : totC - 1;
        const float4* __restrict__ row = (const float4*)(xc + (long)cc * CF_IN);

        float acc[HID];
#pragma unroll
        for (int j = 0; j < HID; ++j) acc[j] = sm[CB1 + j];
#pragma unroll
        for (int k4 = 0; k4 < CF_IN / 4; ++k4) {
            const float4 xv = row[k4];
#pragma unroll
            for (int r = 0; r < 4; ++r) {
                const int k = 4 * k4 + r;
                const float xs = (r == 0) ? xv.x : (r == 1) ? xv.y
                               : (r == 2) ? xv.z : xv.w;
                const float4 w0 = *(const float4*)&sm[CW1 + k * HID + 0];
                const float4 w1 = *(const float4*)&sm[CW1 + k * HID + 4];
                const float4 w2 = *(const float4*)&sm[CW1 + k * HID + 8];
                const float4 w3 = *(const float4*)&sm[CW1 + k * HID + 12];
                acc[0]  = fmaf(xs, w0.x, acc[0]);  acc[1]  = fmaf(xs, w0.y, acc[1]);
                acc[2]  = fmaf(xs, w0.z, acc[2]);  acc[3]  = fmaf(xs, w0.w, acc[3]);
                acc[4]  = fmaf(xs, w1.x, acc[4]);  acc[5]  = fmaf(xs, w1.y, acc[5]);
                acc[6]  = fmaf(xs, w1.z, acc[6]);  acc[7]  = fmaf(xs, w1.w, acc[7]);
                acc[8]  = fmaf(xs, w2.x, acc[8]);  acc[9]  = fmaf(xs, w2.y, acc[9]);
                acc[10] = fmaf(xs, w2.z, acc[10]); acc[11] = fmaf(xs, w2.w, acc[11]);
                acc[12] = fmaf(xs, w3.x, acc[12]); acc[13] = fmaf(xs, w3.y, acc[13]);
                acc[14] = fmaf(xs, w3.z, acc[14]); acc[15] = fmaf(xs, w3.w, acc[15]);
            }
        }
        float o = sm[CB2];
#pragma unroll
        for (int j = 0; j < HID; ++j) o = fmaf(fmaxf(acc[j], 0.f), sm[CW2 + j], o);

        const int myb = c / C;
        const float contrib = (c < totC) ? o : 0.f;
        for (int b = 0; b < B; ++b) {
            float s = (myb == b) ? contrib : 0.f;
#pragma unroll
            for (int off = 32; off; off >>= 1) s += __shfl_down(s, off, 64);
            if ((t & 63) == 0) sm[CPS + wave * B + b] = s;
        }
        __syncthreads();
        if (t == 0) {
            for (int b = 0; b < B; ++b)
                pC[(long)b * colBlocks + cb] =
                    (sm[CPS + 0 * B + b] + sm[CPS + 1 * B + b]) +
                    (sm[CPS + 2 * B + b] + sm[CPS + 3 * B + b]);
        }
    }
}

__global__ __launch_bounds__(256) void finish_kernel(
    const float* __restrict__ pN, const float* __restrict__ pC,
    const float* __restrict__ Wf, const float* __restrict__ bf,
    const float* __restrict__ Wo, const float* __restrict__ bo,
    float* __restrict__ out, int nWN, int nWC, int N, int C, int B)
{
    const int t = threadIdx.x;
    const int wave = t >> 6, lane = t & 63;
    __shared__ float s[16];

    for (int p = wave; p < 2 * B; p += 4) {
        const int b = p >> 1, kind = p & 1;
        float v = 0.f;
        if (kind == 0) {
            for (int i = lane; i < nWN; i += 64) v += pN[(long)b * nWN + i];
        } else {
            for (int i = lane; i < nWC; i += 64) v += pC[(long)b * nWC + i];
        }
#pragma unroll
        for (int off = 32; off; off >>= 1) v += __shfl_down(v, off, 64);
        if (lane == 0) s[p] = v;
    }
    __syncthreads();

    if (t == 0) {
        for (int b = 0; b < B; ++b) {
            const float navg = s[2 * b + 0] / (float)N;
            const float cavg = s[2 * b + 1] / (float)C;
            float o = bo[0];
#pragma unroll
            for (int j = 0; j < HID; ++j) {
                const float h = fmaf(navg, Wf[j], fmaf(cavg, Wf[HID + j], bf[j]));
                o = fmaf(fmaxf(h, 0.f), Wo[j], o);
            }
            out[b] = o;
        }
    }
}

extern "C" void kernel_launch(void* const* d_in, const int* in_sizes, int n_in,
                              void* d_out, int out_size, void* d_ws, size_t ws_size,
                              hipStream_t stream) {
    const float* x   = (const float*)d_in[0];
    const float* xc  = (const float*)d_in[1];
    // d_in[2] = edge_index: unused (row==col degeneracy -> GCN aggregation is identity)
    const float* W1  = (const float*)d_in[3];
    const float* b1  = (const float*)d_in[4];
    const float* W2  = (const float*)d_in[5];
    const float* b2  = (const float*)d_in[6];
    const float* Wn  = (const float*)d_in[7];
    const float* bn  = (const float*)d_in[8];
    const float* Wc1 = (const float*)d_in[9];
    const float* bc1 = (const float*)d_in[10];
    const float* Wc2 = (const float*)d_in[11];
    const float* bc2 = (const float*)d_in[12];
    const float* Wf  = (const float*)d_in[13];
    const float* bf  = (const float*)d_in[14];
    const float* Wo  = (const float*)d_in[15];
    const float* bo  = (const float*)d_in[16];

    const int C = 1000;
    const int B = in_sizes[1] / (C * CF_IN);     // col_features [B, 1000, 64]
    const int N = in_sizes[0] / (B * F_IN);      // node_features [B, N, 128]
    const int totalN = B * N;

    const int nodeBlocks = (totalN + TILE - 1) / TILE;     // 3125
    const int colBlocks  = (B * C + NTHR - 1) / NTHR;      // 8

    float* pN = (float*)d_ws;                    // [B][nodeBlocks], always overwritten
    float* pC = pN + (long)B * nodeBlocks;       // [B][colBlocks]

    fused_kernel<<<nodeBlocks + colBlocks, NTHR, 0, stream>>>(
        x, xc, W1, b1, W2, b2, Wn, bn, Wc1, bc1, Wc2, bc2,
        pN, pC, totalN, N, B, C, nodeBlocks, colBlocks);
    finish_kernel<<<1, 256, 0, stream>>>(pN, pC, Wf, bf, Wo, bo, (float*)d_out,
                                         nodeBlocks, colBlocks, N, C, B);
}

// Round 5
// 38.606 us; speedup vs baseline: 1.4548x; 1.4548x over previous
//
#include <hip/hip_runtime.h>

#define F_IN  128
#define HID   16
#define CF_IN 64
#define NTHR  256

// ---- LDS float offsets (node path) ----
#define SW1   0        // [128][16] = 2048 floats
#define SW2   2048     // [16][16]  = 256
#define SB1   2304     // [16]
#define SB2   2320     // [16]
#define SWN   2336     // [16]
#define SBN   2352     // [1]
#define SPART 2356     // [4]
#define SMF   2364     // 9456 B -> occupancy not LDS-limited
// ---- col path (reuses same buffer) ----
#define CW1   0        // [64][16] = 1024
#define CB1   1024
#define CW2   1040
#define CB2   1056
#define CPART 1060

// GCN aggregation is exactly the identity here (row==col after the reference's
// broadcast+reshape), so each conv is x@W + b. edge_index is never read.
//
// Structure = round-1 (empirical best): thread-per-node, register accumulators,
// per-thread float4 row streaming. Single delta: weights live in LDS and are
// read with wave-uniform broadcast ds_read_b128 (no L1 thrash from the x
// stream, no dependence on compiler scalarization).

__global__ __launch_bounds__(NTHR) void fused_kernel(
    const float* __restrict__ x, const float* __restrict__ xc,
    const float* __restrict__ W1, const float* __restrict__ b1,
    const float* __restrict__ W2, const float* __restrict__ b2,
    const float* __restrict__ Wn, const float* __restrict__ bn,
    const float* __restrict__ Wc1, const float* __restrict__ bc1,
    const float* __restrict__ Wc2, const float* __restrict__ bc2,
    float* __restrict__ pN, float* __restrict__ pC,
    int N, int C, int nodeBlocksPerB, int colBlocksPerB)
{
    __shared__ __align__(16) float sm[SMF];
    float4* sm4 = (float4*)sm;
    const int t = threadIdx.x;
    const int bx = blockIdx.x;
    const int b  = blockIdx.y;

    if (bx < nodeBlocksPerB) {
        // ---------------- node path ----------------
        // stage weights (W1: 512 float4, 2 per thread)
        const float4* __restrict__ gW1 = (const float4*)W1;
        sm4[t] = gW1[t];
        sm4[NTHR + t] = gW1[NTHR + t];
        if (t < HID * HID / 4) sm4[SW2 / 4 + t] = ((const float4*)W2)[t];
        if (t < HID) { sm[SB1 + t] = b1[t]; sm[SB2 + t] = b2[t]; sm[SWN + t] = Wn[t]; }
        if (t == 0)  sm[SBN] = bn[0];
        __syncthreads();

        const int n = bx * NTHR + t;            // node within batch b
        const bool valid = (n < N);
        const int nc = valid ? n : N - 1;
        const float4* __restrict__ row =
            (const float4*)(x + ((size_t)b * N + nc) * F_IN);

        float acc[HID];
#pragma unroll
        for (int j = 0; j < HID; ++j) acc[j] = sm[SB1 + j];

#pragma unroll 8
        for (int k4 = 0; k4 < F_IN / 4; ++k4) {
            const float4 xv = row[k4];
#pragma unroll
            for (int r = 0; r < 4; ++r) {
                const int k = 4 * k4 + r;
                const float xs = (r == 0) ? xv.x : (r == 1) ? xv.y
                               : (r == 2) ? xv.z : xv.w;
                const float4 w0 = *(const float4*)&sm[SW1 + k * HID + 0];
                const float4 w1 = *(const float4*)&sm[SW1 + k * HID + 4];
                const float4 w2 = *(const float4*)&sm[SW1 + k * HID + 8];
                const float4 w3 = *(const float4*)&sm[SW1 + k * HID + 12];
                acc[0]  = fmaf(xs, w0.x, acc[0]);  acc[1]  = fmaf(xs, w0.y, acc[1]);
                acc[2]  = fmaf(xs, w0.z, acc[2]);  acc[3]  = fmaf(xs, w0.w, acc[3]);
                acc[4]  = fmaf(xs, w1.x, acc[4]);  acc[5]  = fmaf(xs, w1.y, acc[5]);
                acc[6]  = fmaf(xs, w1.z, acc[6]);  acc[7]  = fmaf(xs, w1.w, acc[7]);
                acc[8]  = fmaf(xs, w2.x, acc[8]);  acc[9]  = fmaf(xs, w2.y, acc[9]);
                acc[10] = fmaf(xs, w2.z, acc[10]); acc[11] = fmaf(xs, w2.w, acc[11]);
                acc[12] = fmaf(xs, w3.x, acc[12]); acc[13] = fmaf(xs, w3.y, acc[13]);
                acc[14] = fmaf(xs, w3.z, acc[14]); acc[15] = fmaf(xs, w3.w, acc[15]);
            }
        }

        // layer 2 (16x16) + relu, layer 3 (16->1); broadcast LDS reads
        float h1[HID];
#pragma unroll
        for (int j = 0; j < HID; ++j) h1[j] = fmaxf(acc[j], 0.f);
        float h2[HID];
#pragma unroll
        for (int j = 0; j < HID; ++j) h2[j] = sm[SB2 + j];
#pragma unroll
        for (int kk = 0; kk < HID; ++kk) {
            const float hk = h1[kk];
            const float4 w0 = *(const float4*)&sm[SW2 + kk * HID + 0];
            const float4 w1 = *(const float4*)&sm[SW2 + kk * HID + 4];
            const float4 w2 = *(const float4*)&sm[SW2 + kk * HID + 8];
            const float4 w3 = *(const float4*)&sm[SW2 + kk * HID + 12];
            h2[0]  = fmaf(hk, w0.x, h2[0]);  h2[1]  = fmaf(hk, w0.y, h2[1]);
            h2[2]  = fmaf(hk, w0.z, h2[2]);  h2[3]  = fmaf(hk, w0.w, h2[3]);
            h2[4]  = fmaf(hk, w1.x, h2[4]);  h2[5]  = fmaf(hk, w1.y, h2[5]);
            h2[6]  = fmaf(hk, w1.z, h2[6]);  h2[7]  = fmaf(hk, w1.w, h2[7]);
            h2[8]  = fmaf(hk, w2.x, h2[8]);  h2[9]  = fmaf(hk, w2.y, h2[9]);
            h2[10] = fmaf(hk, w2.z, h2[10]); h2[11] = fmaf(hk, w2.w, h2[11]);
            h2[12] = fmaf(hk, w3.x, h2[12]); h2[13] = fmaf(hk, w3.y, h2[13]);
            h2[14] = fmaf(hk, w3.z, h2[14]); h2[15] = fmaf(hk, w3.w, h2[15]);
        }
        float o = sm[SBN];
#pragma unroll
        for (int kk = 0; kk < HID; ++kk)
            o = fmaf(fmaxf(h2[kk], 0.f), sm[SWN + kk], o);

        float val = valid ? o : 0.f;
#pragma unroll
        for (int off = 32; off; off >>= 1) val += __shfl_down(val, off, 64);
        if ((t & 63) == 0) sm[SPART + (t >> 6)] = val;
        __syncthreads();
        if (t == 0)
            pN[(size_t)b * nodeBlocksPerB + bx] =
                (sm[SPART + 0] + sm[SPART + 1]) + (sm[SPART + 2] + sm[SPART + 3]);
    } else {
        // ---------------- col path ----------------
        const int cb = bx - nodeBlocksPerB;
        const float4* __restrict__ gWc1 = (const float4*)Wc1;
        if (t < CF_IN * HID / 4) sm4[CW1 / 4 + t] = gWc1[t];
        if (t < HID) { sm[CB1 + t] = bc1[t]; sm[CW2 + t] = Wc2[t]; }
        if (t == 0)  sm[CB2] = bc2[0];
        __syncthreads();

        const int c = cb * NTHR + t;
        const bool valid = (c < C);
        const int cc = valid ? c : C - 1;
        const float4* __restrict__ row =
            (const float4*)(xc + ((size_t)b * C + cc) * CF_IN);

        float acc[HID];
#pragma unroll
        for (int j = 0; j < HID; ++j) acc[j] = sm[CB1 + j];
#pragma unroll
        for (int k4 = 0; k4 < CF_IN / 4; ++k4) {
            const float4 xv = row[k4];
#pragma unroll
            for (int r = 0; r < 4; ++r) {
                const int k = 4 * k4 + r;
                const float xs = (r == 0) ? xv.x : (r == 1) ? xv.y
                               : (r == 2) ? xv.z : xv.w;
                const float4 w0 = *(const float4*)&sm[CW1 + k * HID + 0];
                const float4 w1 = *(const float4*)&sm[CW1 + k * HID + 4];
                const float4 w2 = *(const float4*)&sm[CW1 + k * HID + 8];
                const float4 w3 = *(const float4*)&sm[CW1 + k * HID + 12];
                acc[0]  = fmaf(xs, w0.x, acc[0]);  acc[1]  = fmaf(xs, w0.y, acc[1]);
                acc[2]  = fmaf(xs, w0.z, acc[2]);  acc[3]  = fmaf(xs, w0.w, acc[3]);
                acc[4]  = fmaf(xs, w1.x, acc[4]);  acc[5]  = fmaf(xs, w1.y, acc[5]);
                acc[6]  = fmaf(xs, w1.z, acc[6]);  acc[7]  = fmaf(xs, w1.w, acc[7]);
                acc[8]  = fmaf(xs, w2.x, acc[8]);  acc[9]  = fmaf(xs, w2.y, acc[9]);
                acc[10] = fmaf(xs, w2.z, acc[10]); acc[11] = fmaf(xs, w2.w, acc[11]);
                acc[12] = fmaf(xs, w3.x, acc[12]); acc[13] = fmaf(xs, w3.y, acc[13]);
                acc[14] = fmaf(xs, w3.z, acc[14]); acc[15] = fmaf(xs, w3.w, acc[15]);
            }
        }
        float o = sm[CB2];
#pragma unroll
        for (int j = 0; j < HID; ++j)
            o = fmaf(fmaxf(acc[j], 0.f), sm[CW2 + j], o);

        float val = valid ? o : 0.f;
#pragma unroll
        for (int off = 32; off; off >>= 1) val += __shfl_down(val, off, 64);
        if ((t & 63) == 0) sm[CPART + (t >> 6)] = val;
        __syncthreads();
        if (t == 0)
            pC[(size_t)b * colBlocksPerB + cb] =
                (sm[CPART + 0] + sm[CPART + 1]) + (sm[CPART + 2] + sm[CPART + 3]);
    }
}

__global__ __launch_bounds__(256) void finish_kernel(
    const float* __restrict__ pN, const float* __restrict__ pC,
    const float* __restrict__ Wf, const float* __restrict__ bf,
    const float* __restrict__ Wo, const float* __restrict__ bo,
    float* __restrict__ out, int nWN, int nWC, int N, int C, int B)
{
    const int t = threadIdx.x;
    const int wave = t >> 6, lane = t & 63;
    __shared__ float s[16];

    for (int p = wave; p < 2 * B; p += 4) {
        const int b = p >> 1, kind = p & 1;
        float v = 0.f;
        if (kind == 0) {
            for (int i = lane; i < nWN; i += 64) v += pN[(size_t)b * nWN + i];
        } else {
            for (int i = lane; i < nWC; i += 64) v += pC[(size_t)b * nWC + i];
        }
#pragma unroll
        for (int off = 32; off; off >>= 1) v += __shfl_down(v, off, 64);
        if (lane == 0) s[p] = v;
    }
    __syncthreads();

    if (t == 0) {
        for (int b = 0; b < B; ++b) {
            const float navg = s[2 * b + 0] / (float)N;
            const float cavg = s[2 * b + 1] / (float)C;
            float o = bo[0];
#pragma unroll
            for (int j = 0; j < HID; ++j) {
                const float h = fmaf(navg, Wf[j], fmaf(cavg, Wf[HID + j], bf[j]));
                o = fmaf(fmaxf(h, 0.f), Wo[j], o);
            }
            out[b] = o;
        }
    }
}

extern "C" void kernel_launch(void* const* d_in, const int* in_sizes, int n_in,
                              void* d_out, int out_size, void* d_ws, size_t ws_size,
                              hipStream_t stream) {
    const float* x   = (const float*)d_in[0];
    const float* xc  = (const float*)d_in[1];
    // d_in[2] = edge_index: unused (row==col degeneracy -> GCN aggregation is identity)
    const float* W1  = (const float*)d_in[3];
    const float* b1  = (const float*)d_in[4];
    const float* W2  = (const float*)d_in[5];
    const float* b2  = (const float*)d_in[6];
    const float* Wn  = (const float*)d_in[7];
    const float* bn  = (const float*)d_in[8];
    const float* Wc1 = (const float*)d_in[9];
    const float* bc1 = (const float*)d_in[10];
    const float* Wc2 = (const float*)d_in[11];
    const float* bc2 = (const float*)d_in[12];
    const float* Wf  = (const float*)d_in[13];
    const float* bf  = (const float*)d_in[14];
    const float* Wo  = (const float*)d_in[15];
    const float* bo  = (const float*)d_in[16];

    const int C = 1000;
    const int B = in_sizes[1] / (C * CF_IN);     // col_features [B, 1000, 64]
    const int N = in_sizes[0] / (B * F_IN);      // node_features [B, N, 128]

    const int nodeBlocksPerB = (N + NTHR - 1) / NTHR;   // 391
    const int colBlocksPerB  = (C + NTHR - 1) / NTHR;   // 4

    float* pN = (float*)d_ws;                        // [B][nodeBlocksPerB], always overwritten
    float* pC = pN + (size_t)B * nodeBlocksPerB;     // [B][colBlocksPerB]

    fused_kernel<<<dim3(nodeBlocksPerB + colBlocksPerB, B), NTHR, 0, stream>>>(
        x, xc, W1, b1, W2, b2, Wn, bn, Wc1, bc1, Wc2, bc2,
        pN, pC, N, C, nodeBlocksPerB, colBlocksPerB);
    finish_kernel<<<1, 256, 0, stream>>>(pN, pC, Wf, bf, Wo, bo, (float*)d_out,
                                         nodeBlocksPerB, colBlocksPerB, N, C, B);
}